// Round 16
// baseline (45.909 us; speedup 1.0000x reference)
//
#include <hip/hip_runtime.h>

constexpr int NPTS  = 1024;   // points per batch
constexpr int NT    = 21;     // targets per batch
constexpr int KSEL  = 64;     // top-k
constexpr int BLOCK = 256;    // 4 waves, 1 wave per (b,t)
constexpr int PPL   = 16;     // points per lane (1024 / 64)
constexpr int NXCD  = 8;

typedef float f32x4 __attribute__((ext_vector_type(4)));

__device__ __forceinline__ unsigned key_of(float d) {
    // monotone float->uint transform (total order matching float <)
    unsigned u = __float_as_uint(d);
    return (u & 0x80000000u) ? ~u : (u | 0x80000000u);
}

__device__ __forceinline__ unsigned mbcnt64(unsigned long long m) {
    unsigned lo = __builtin_amdgcn_mbcnt_lo((unsigned)m, 0u);
    return __builtin_amdgcn_mbcnt_hi((unsigned)(m >> 32), lo);
}

__global__ __launch_bounds__(BLOCK) void knn_mask_fullline_kernel(
    const float* __restrict__ pc,   // (B, 1024, 3)
    const float* __restrict__ tgt,  // (B, 21, 3)
    float* __restrict__ out,        // (B, 21, 1024, 3)
    int total_bt)
{
    const int wave = threadIdx.x >> 6;
    const int lane = threadIdx.x & 63;
    // bijective XCD swizzle (gridDim.x divisible by 8)
    const int cpx  = gridDim.x / NXCD;
    const int sbid = ((int)blockIdx.x % NXCD) * cpx + (int)blockIdx.x / NXCD;
    const int bt   = sbid * 4 + wave;
    if (bt >= total_bt) return;          // wave-uniform
    const int b  = bt / NT;
    const int tq = bt % NT;

    const float* base  = pc  + (size_t)b  * (NPTS * 3);
    float*       obase = out + (size_t)bt * (NPTS * 3);
    const f32x4* src4  = reinterpret_cast<const f32x4*>(base);
    f32x4*       dst4  = reinterpret_cast<f32x4*>(obase);

    // per-wave 1024-bit select bitmap: word w = points 32w..32w+31 (+ guard)
    __shared__ unsigned sbm[4][33];

    // ---- phase 0: select-independent zeroing of the whole output row ----
    {
        const f32x4 z = {0.0f, 0.0f, 0.0f, 0.0f};
        #pragma unroll
        for (int j = 0; j < 12; ++j) dst4[64 * j + lane] = z;
    }

    // target point (wave-uniform, L1-broadcast)
    const float* tp = tgt + ((size_t)b * NT + tq) * 3;
    const float  t0 = tp[0], t1 = tp[1], t2 = tp[2];
    const float  dt = t0 * t0 + t1 * t1 + t2 * t2;

    // ---- phase 1: strided ownership (lane owns points 64*i + lane) ----
    unsigned key[PPL];
    #pragma unroll
    for (int i = 0; i < PPL; ++i) {
        const float* pp = base + 3 * (64 * i + lane);
        const float p0 = pp[0], p1 = pp[1], p2 = pp[2];
        const float d  = dt + (p0 * p0 + p1 * p1 + p2 * p2)
                            - 2.0f * (t0 * p0 + t1 * p1 + t2 * p2);
        key[i] = key_of(d);
    }

    // ---- phase 2: threshold-form exact select of the KSEL-th smallest ----
    unsigned kand = key[0], kor = key[0];
    #pragma unroll
    for (int i = 1; i < PPL; ++i) { kand &= key[i]; kor |= key[i]; }
    #pragma unroll
    for (int off = 32; off > 0; off >>= 1) {
        kand &= (unsigned)__shfl_xor((int)kand, off, 64);
        kor  |= (unsigned)__shfl_xor((int)kor,  off, 64);
    }
    const unsigned dis = kor & ~kand;    // bits where keys disagree

    unsigned lo = 0, below = 0, want = KSEL, cls = NPTS;
    bool     early = false;
    unsigned Tsel = 0, kth = 0;
    if (dis == 0u) {
        kth = kand;                       // all 1024 keys identical
    } else {
        const int hb = 31 - __builtin_clz(dis);
        lo = (hb == 31) ? 0u : (kand & (~0u << (hb + 1)));  // common high bits
        for (int s = hb; s >= 0; --s) {
            const unsigned mid = lo | (1u << s);
            unsigned cnt = 0;
            #pragma unroll
            for (int i = 0; i < PPL; ++i) cnt += (key[i] < mid) ? 1u : 0u;
            unsigned c = 0;               // wave total via 5-ballot decompose
            #pragma unroll
            for (int j = 0; j < 5; ++j)
                c += (unsigned)__popcll(__ballot((cnt >> j) & 1u)) << j;
            const unsigned t = c - below; // size of class-0 = [lo, mid)
            if (want <= t) { cls = t; }
            else { want -= t; below = c; lo = mid; cls -= t; }
            if (cls == want) { early = true; Tsel = lo + (1u << s); break; }
        }
        if (!early) kth = lo;
    }

    // ---- phase 3: selection flags. bit i => point (64*i + lane). ----
    unsigned selmask = 0;
    if (early) {
        #pragma unroll
        for (int i = 0; i < PPL; ++i)
            if (key[i] < Tsel) selmask |= (1u << i);
    } else {
        unsigned run_tot = 0;   // stable lowest-index ties: index = 64*i + lane
        #pragma unroll
        for (int i = 0; i < PPL; ++i) {
            const bool eq = (key[i] == kth);
            const unsigned long long bal = __ballot(eq);
            const bool sel_eq = eq && (run_tot + mbcnt64(bal)) < want;
            if (key[i] < kth || sel_eq) selmask |= (1u << i);
            run_tot += (unsigned)__popcll(bal);
        }
    }

    // ---- phase 3b: materialize full 1024-bit bitmap in per-wave LDS.
    // word w covers points 32w..32w+31; bit of point p = bit (p&31).
    // point p's select bit lives in lane (p&63), bit (p>>6):
    //   ballot((selmask>>i)&1) = 64-bit mask over points 64i..64i+63.
    {
        unsigned myword = 0;
        #pragma unroll
        for (int w = 0; w < 16; ++w) {
            const unsigned long long bal = __ballot((selmask >> w) & 1u);
            const unsigned lo32 = (unsigned)bal, hi32 = (unsigned)(bal >> 32);
            if ((lane >> 1) == w) myword = (lane & 1) ? hi32 : lo32;
        }
        if (lane < 32) sbm[wave][lane] = myword;
        if (lane == 32) sbm[wave][32] = 0u;   // guard word
        // same-wave LDS produce->consume: DS pipe is in-order per wave;
        // compiler inserts lgkmcnt before dependent ds_read.
    }

    // ---- phase 4: full-64B-line value stores (no partial-line RMW).
    // vmcnt(0) orders vs the phase-0 zero stores. For each selected point,
    // rewrite the containing line(s) completely: values from L1-hot pc,
    // blend bits from the LDS bitmap. Duplicate line writes carry identical
    // content (both lanes compute from the same bitmap) -> benign WAW.
    asm volatile("s_waitcnt vmcnt(0)" ::: "memory");
    unsigned sm = selmask;
    while (sm) {
        const int i = __builtin_ctz(sm);
        sm &= sm - 1u;
        const int q     = 64 * i + lane;
        const int byte0 = 12 * q;
        const int L0 = byte0 >> 6;
        const int L1 = (byte0 + 11) >> 6;    // 12.5% of points span 2 lines
        #pragma unroll 1
        for (int L = L0; L <= L1; ++L) {
            const unsigned f0 = (unsigned)L << 4;             // first float of line
            const unsigned q0 = (f0 * 21846u) >> 16;          // floor(f0/3), exact for f0<21845
            const unsigned d0 = f0 - 3u * q0;                 // 0..2
            const unsigned wi = q0 >> 5;
            const unsigned w0 = sbm[wave][wi];
            const unsigned w1 = sbm[wave][wi + 1];            // guard covers wi=31
            const unsigned win =
                (unsigned)((((unsigned long long)w1 << 32) | w0) >> (q0 & 31u));
            // expand point-bits (q0..q0+5) into float-bits, align to f0
            unsigned fm = 0;
            #pragma unroll
            for (int bb = 0; bb < 6; ++bb)
                fm |= ((win >> bb) & 1u) * (7u << (3 * bb));
            fm >>= d0;                                        // bit j = float f0+j
            #pragma unroll
            for (int k = 0; k < 4; ++k) {
                const f32x4 g = src4[4 * L + k];              // L1-hot
                f32x4 v;
                v.x = ((fm >> (4 * k + 0)) & 1u) ? g.x : 0.0f;
                v.y = ((fm >> (4 * k + 1)) & 1u) ? g.y : 0.0f;
                v.z = ((fm >> (4 * k + 2)) & 1u) ? g.z : 0.0f;
                v.w = ((fm >> (4 * k + 3)) & 1u) ? g.w : 0.0f;
                dst4[4 * L + k] = v;
            }
        }
    }
}

extern "C" void kernel_launch(void* const* d_in, const int* in_sizes, int n_in,
                              void* d_out, int out_size, void* d_ws, size_t ws_size,
                              hipStream_t stream) {
    const float* pc  = (const float*)d_in[0];  // (B,1024,3)
    const float* tgt = (const float*)d_in[1];  // (B,21,3)
    float*       out = (float*)d_out;          // (B,21,1024,3)

    const int B        = in_sizes[0] / (NPTS * 3);   // 512
    const int total_bt = B * NT;                      // 10752
    const int nblocks  = (total_bt + 3) / 4;          // 2688 (divisible by 8)

    knn_mask_fullline_kernel<<<nblocks, BLOCK, 0, stream>>>(pc, tgt, out, total_bt);
}